// Round 1
// 1404.482 us; speedup vs baseline: 1.5187x; 1.5187x over previous
//
#include <hip/hip_runtime.h>
#include <math.h>
#include <stdint.h>

// ---------------- constants ----------------
#define BATCH 2
#define NIN   1024
#define NSEQ  2048
#define DIMC  512
#define NH    8
#define DHD   64
#define MLM   17
#define LBLK  125
#define SEQ   2117      // 1 + 2116
#define NPAD  2125      // SEQ + 8
#define PAD0  8
#define HS    46
#define NPIX  2116      // 46*46
#define RA    4250      // BATCH*NPAD rows of the stacked activation matrices
#define AWSZ  ((size_t)BATCH*NH*NPAD*NPAD)   // 72,250,000

typedef _Float16 half8 __attribute__((ext_vector_type(8)));
typedef float    floatx4 __attribute__((ext_vector_type(4)));

// write one fp32 value as hi/lo _Float16 pair in granule-major layout [k/8][row][8]
__device__ __forceinline__ void store_hl(_Float16* __restrict__ xh, _Float16* __restrict__ xl,
                                         int c, int ra, float v)
{
    _Float16 hv = (_Float16)v;
    size_t o = ((size_t)(c >> 3) * RA + ra) * 8 + (c & 7);
    xh[o] = hv;
    xl[o] = (_Float16)(v - (float)hv);
}

// ---------------- conversion: A fp32 [R][K] -> granule-major hi/lo halves ----------------
__global__ void convA_kernel(const float* __restrict__ X, _Float16* __restrict__ hi,
                             _Float16* __restrict__ lo, int R, int K)
{
    int GK = K >> 3;
    size_t idx = (size_t)blockIdx.x * 256 + threadIdx.x;
    if (idx >= (size_t)R * GK) return;
    int r = (int)(idx % R); int gk = (int)(idx / R);
    const float* s = X + (size_t)r * K + gk * 8;
    half8 h, l;
    #pragma unroll
    for (int j = 0; j < 8; ++j) {
        float x = s[j];
        _Float16 hh = (_Float16)x;
        h[j] = hh;
        l[j] = (_Float16)(x - (float)hh);
    }
    *(half8*)(hi + idx * 8) = h;   // offset == ((size_t)gk*R + r)*8
    *(half8*)(lo + idx * 8) = l;
}

// ---------------- conversion: B fp32 [K][N] -> B^T granule-major hi/lo halves ----------------
__global__ void convB_kernel(const float* __restrict__ X, _Float16* __restrict__ hi,
                             _Float16* __restrict__ lo, int N, int K)
{
    int GK = K >> 3;
    size_t idx = (size_t)blockIdx.x * 256 + threadIdx.x;
    if (idx >= (size_t)N * GK) return;
    int n = (int)(idx % N); int gk = (int)(idx / N);
    const float* s = X + (size_t)(gk * 8) * N + n;
    half8 h, l;
    #pragma unroll
    for (int j = 0; j < 8; ++j) {
        float x = s[(size_t)j * N];
        _Float16 hh = (_Float16)x;
        h[j] = hh;
        l[j] = (_Float16)(x - (float)hh);
    }
    *(half8*)(hi + idx * 8) = h;
    *(half8*)(lo + idx * 8) = l;
}

// ---------------- MFMA GEMM: C = A(MxK) @ B(KxN) (+bias)(+relu), f16x3 split ----------------
// A,B supplied as granule-major hi/lo halves: A[k/8][m][8], B^T[k/8][n][8].
// 128x128 tile, 4 waves each 64x64, K-step 32, 16x16x32_f16 MFMA.
__global__ __launch_bounds__(256) void gemm_mfma(
    const _Float16* __restrict__ Ah, const _Float16* __restrict__ Al,
    const _Float16* __restrict__ Bh, const _Float16* __restrict__ Bl,
    const float* __restrict__ bias, float* __restrict__ C,
    int Mn, int Nn, int Kn, int relu)
{
    __shared__ _Float16 sA[2][4][128][8];   // [hi/lo][granule][row][8]  -> 16 KB
    __shared__ _Float16 sB[2][4][128][8];   // 16 KB
    const int tid = threadIdx.x;
    const int wv = tid >> 6, ln = tid & 63;
    const int m0 = blockIdx.y * 128, n0 = blockIdx.x * 128;
    const int wm = (wv >> 1) * 64, wn = (wv & 1) * 64;
    const int g = ln >> 4, rr = ln & 15;

    floatx4 acc[4][4];
    #pragma unroll
    for (int m = 0; m < 4; ++m)
        #pragma unroll
        for (int n = 0; n < 4; ++n)
            acc[m][n] = (floatx4){0.f, 0.f, 0.f, 0.f};

    for (int k0 = 0; k0 < Kn; k0 += 32) {
        int gk0 = k0 >> 3;
        // stage 32 KB: 32 chunks of 1 KB (64 rows x 16B); wave wv owns chunks c== wv (mod 4)
        #pragma unroll
        for (int q2 = 0; q2 < 8; ++q2) {
            int c = wv + q2 * 4;
            int arr = c >> 3, gg = (c >> 1) & 3, hf = c & 1;
            const _Float16* base = (arr == 0) ? Ah : (arr == 1) ? Al : (arr == 2) ? Bh : Bl;
            int Rdim = (arr < 2) ? Mn : Nn;
            int rg = ((arr < 2) ? m0 : n0) + hf * 64 + ln;
            if (arr < 2 && rg >= Mn) rg = Mn - 1;   // clamp tail rows (stores are guarded)
            const _Float16* src = base + ((size_t)(gk0 + gg) * Rdim + rg) * 8;
            _Float16* dst = (arr == 0) ? &sA[0][gg][hf * 64][0] :
                            (arr == 1) ? &sA[1][gg][hf * 64][0] :
                            (arr == 2) ? &sB[0][gg][hf * 64][0] :
                                         &sB[1][gg][hf * 64][0];
            __builtin_amdgcn_global_load_lds(
                (__attribute__((address_space(1))) void*)(uintptr_t)src,
                (__attribute__((address_space(3))) void*)dst, 16, 0, 0);
        }
        __syncthreads();

        half8 a_h[4], a_l[4], b_h[4], b_l[4];
        #pragma unroll
        for (int m = 0; m < 4; ++m) {
            a_h[m] = *(const half8*)&sA[0][g][wm + m * 16 + rr][0];
            a_l[m] = *(const half8*)&sA[1][g][wm + m * 16 + rr][0];
        }
        #pragma unroll
        for (int n = 0; n < 4; ++n) {
            b_h[n] = *(const half8*)&sB[0][g][wn + n * 16 + rr][0];
            b_l[n] = *(const half8*)&sB[1][g][wn + n * 16 + rr][0];
        }
        #pragma unroll
        for (int m = 0; m < 4; ++m)
            #pragma unroll
            for (int n = 0; n < 4; ++n) {
                acc[m][n] = __builtin_amdgcn_mfma_f32_16x16x32_f16(a_h[m], b_h[n], acc[m][n], 0, 0, 0);
                acc[m][n] = __builtin_amdgcn_mfma_f32_16x16x32_f16(a_l[m], b_h[n], acc[m][n], 0, 0, 0);
                acc[m][n] = __builtin_amdgcn_mfma_f32_16x16x32_f16(a_h[m], b_l[n], acc[m][n], 0, 0, 0);
            }
        __syncthreads();
    }

    // epilogue: C/D layout col = lane&15, row = (lane>>4)*4 + r
    const int rq = ln >> 4;
    #pragma unroll
    for (int n = 0; n < 4; ++n) {
        int col = n0 + wn + n * 16 + rr;
        float bv = bias ? bias[col] : 0.f;
        #pragma unroll
        for (int m = 0; m < 4; ++m) {
            #pragma unroll
            for (int r = 0; r < 4; ++r) {
                int row = m0 + wm + m * 16 + rq * 4 + r;
                if (row < Mn) {
                    float vv = acc[m][n][r] + bv;
                    if (relu) vv = fmaxf(vv, 0.f);
                    C[(size_t)row * Nn + col] = vv;
                }
            }
        }
    }
}

// ---------------- build h: cls + fc1out + wrap ----------------
__global__ void buildh_kernel(const float* __restrict__ h0, const float* __restrict__ cls,
                              float* __restrict__ h)
{
    size_t e = (size_t)blockIdx.x*256 + threadIdx.x;
    if (e >= (size_t)BATCH*SEQ*DIMC) return;
    int c = e % DIMC; size_t r = e / DIMC;
    int t = r % SEQ; int b = r / SEQ;
    float val;
    if (t == 0) val = cls[c];
    else {
        int n = t - 1;
        if (n >= NSEQ) n -= NSEQ;
        val = h0[((size_t)(b*NSEQ + n))*DIMC + c];
    }
    h[e] = val;
}

// ---------------- LayerNorm rows of h -> granule-major hi/lo halves (rows 0..7 zero) ----------------
__global__ void ln_pad_kernel(const float* __restrict__ h, const float* __restrict__ g,
                              const float* __restrict__ bta,
                              _Float16* __restrict__ xh, _Float16* __restrict__ xl)
{
    int r = blockIdx.x; int b = blockIdx.y; int t = threadIdx.x; // block 256
    int ra = b*NPAD + r;
    if (r < PAD0) {
        store_hl(xh, xl, t, ra, 0.f);
        store_hl(xh, xl, t + 256, ra, 0.f);
        return;
    }
    const float* x = &h[((size_t)(b*SEQ + r-PAD0))*DIMC];
    __shared__ float red[256];
    float x0 = x[t], x1 = x[t+256];
    red[t] = x0 + x1; __syncthreads();
    for (int s=128;s>0;s>>=1){ if(t<s) red[t]+=red[t+s]; __syncthreads(); }
    float mu = red[0] * (1.f/512.f); __syncthreads();
    float d0 = x0-mu, d1 = x1-mu;
    red[t] = d0*d0 + d1*d1; __syncthreads();
    for (int s=128;s>0;s>>=1){ if(t<s) red[t]+=red[t+s]; __syncthreads(); }
    float rstd = 1.0f / sqrtf(red[0]*(1.f/512.f) + 1e-5f);
    store_hl(xh, xl, t,       ra, d0*rstd*g[t]     + bta[t]);
    store_hl(xh, xl, t + 256, ra, d1*rstd*g[t+256] + bta[t+256]);
}

// ---------------- split qkv into head-major q(scaled),k,v ----------------
__global__ void split_heads_kernel(const float* __restrict__ qkv, float* __restrict__ q,
                                   float* __restrict__ k, float* __restrict__ v)
{
    size_t idx = (size_t)blockIdx.x*256 + threadIdx.x;
    if (idx >= (size_t)BATCH*NH*NPAD*DHD) return;
    int d = idx % DHD; size_t r = idx / DHD;
    int i = r % NPAD; r /= NPAD;
    int h = r % NH; int b = r / NH;
    size_t src = ((size_t)(b*NPAD + i))*1536 + h*DHD + d;
    q[idx] = qkv[src] * 0.125f;
    k[idx] = qkv[src + 512];
    v[idx] = qkv[src + 1024];
}

// ---------------- landmarks: mean over 125-blocks ----------------
__global__ void landmark_kernel(const float* __restrict__ q, const float* __restrict__ k,
                                float* __restrict__ ql, float* __restrict__ kl)
{
    int m = blockIdx.x, h = blockIdx.y, b = blockIdx.z, d = threadIdx.x; // 64 thr
    int bh = b*NH + h;
    size_t base = ((size_t)bh*NPAD + m*LBLK)*DHD + d;
    float sq = 0.f, sk = 0.f;
    for (int r=0;r<LBLK;++r){ sq += q[base + (size_t)r*DHD]; sk += k[base + (size_t)r*DHD]; }
    size_t o = ((size_t)bh*MLM + m)*DHD + d;
    ql[o] = sq / 125.f; kl[o] = sk / 125.f;
}

// ---------------- a1 = softmax(q @ kl^T), rows of 17 ----------------
__global__ void a1_kernel(const float* __restrict__ q, const float* __restrict__ kl,
                          float* __restrict__ a1)
{
    int i = blockIdx.x, h = blockIdx.y, b = blockIdx.z;
    int bh = b*NH + h; int lane = threadIdx.x; // 64
    __shared__ float qrow[64];
    __shared__ float dots[MLM];
    qrow[lane] = q[((size_t)bh*NPAD + i)*DHD + lane];
    __syncthreads();
    if (lane < MLM) {
        const float* krow = &kl[((size_t)bh*MLM + lane)*DHD];
        float acc = 0.f;
        for (int d=0; d<DHD; ++d) acc += qrow[d]*krow[d];
        dots[lane] = acc;
    }
    __syncthreads();
    if (lane < MLM) {
        float mx = -1e30f;
        for (int u=0;u<MLM;++u) mx = fmaxf(mx, dots[u]);
        float s = 0.f;
        for (int u=0;u<MLM;++u) s += expf(dots[u]-mx);
        a1[((size_t)bh*NPAD + i)*MLM + lane] = expf(dots[lane]-mx)/s;
    }
}

// ---------------- a2 = softmax(ql @ kl^T), 17x17 per (b,h) ----------------
__global__ void a2_kernel(const float* __restrict__ ql, const float* __restrict__ kl,
                          float* __restrict__ a2)
{
    int bh = blockIdx.x; int t = threadIdx.x; // 320
    __shared__ float s[MLM*MLM];
    if (t < MLM*MLM) {
        int m = t/MLM, j = t%MLM;
        const float* qr = &ql[((size_t)bh*MLM+m)*DHD];
        const float* kr = &kl[((size_t)bh*MLM+j)*DHD];
        float acc=0.f; for(int d=0;d<DHD;++d) acc += qr[d]*kr[d];
        s[t] = acc;
    }
    __syncthreads();
    if (t < MLM*MLM) {
        int m = t/MLM;
        float mx=-1e30f; for(int u=0;u<MLM;++u) mx=fmaxf(mx, s[m*MLM+u]);
        float sm=0.f; for(int u=0;u<MLM;++u) sm += expf(s[m*MLM+u]-mx);
        a2[(size_t)bh*MLM*MLM + t] = expf(s[t]-mx)/sm;
    }
}

// ---------------- a3 = softmax(ql @ k^T), rows of 2125 ----------------
__global__ void a3_kernel(const float* __restrict__ ql, const float* __restrict__ k,
                          float* __restrict__ a3)
{
    int m = blockIdx.x, h = blockIdx.y, b = blockIdx.z;
    int bh = b*NH + h; int tid = threadIdx.x; // 256
    __shared__ float qlrow[64];
    __shared__ float buf[NPAD];
    __shared__ float red[256];
    if (tid < 64) qlrow[tid] = ql[((size_t)bh*MLM+m)*DHD + tid];
    __syncthreads();
    for (int j = tid; j < NPAD; j += 256) {
        const float* kr = &k[((size_t)bh*NPAD + j)*DHD];
        float acc = 0.f;
        for (int d=0; d<DHD; ++d) acc += qlrow[d]*kr[d];
        buf[j] = acc;
    }
    __syncthreads();
    float mx = -1e30f;
    for (int j = tid; j < NPAD; j += 256) mx = fmaxf(mx, buf[j]);
    red[tid] = mx; __syncthreads();
    for (int s=128;s>0;s>>=1){ if(tid<s) red[tid]=fmaxf(red[tid],red[tid+s]); __syncthreads(); }
    mx = red[0]; __syncthreads();
    float sm = 0.f;
    for (int j = tid; j < NPAD; j += 256) sm += expf(buf[j]-mx);
    red[tid] = sm; __syncthreads();
    for (int s=128;s>0;s>>=1){ if(tid<s) red[tid]+=red[tid+s]; __syncthreads(); }
    sm = red[0];
    for (int j = tid; j < NPAD; j += 256)
        a3[((size_t)bh*MLM+m)*NPAD + j] = expf(buf[j]-mx)/sm;
}

// ---------------- pinv init scale (GLOBAL max over b,h) ----------------
__global__ void pinv_scale_kernel(const float* __restrict__ a2, float* __restrict__ scal)
{
    int t = threadIdx.x; // 512
    __shared__ float red[512];
    float rs = -1e30f, cs = -1e30f;
    if (t < BATCH*NH*MLM) {
        int bh = t/MLM, i = t%MLM;
        const float* x = &a2[(size_t)bh*MLM*MLM];
        float r=0.f, c=0.f;
        for (int j=0;j<MLM;++j){ r += fabsf(x[i*MLM+j]); c += fabsf(x[j*MLM+i]); }
        rs = r; cs = c;
    }
    red[t] = rs; __syncthreads();
    for (int s=256;s>0;s>>=1){ if(t<s) red[t]=fmaxf(red[t],red[t+s]); __syncthreads(); }
    float m1 = red[0]; __syncthreads();
    red[t] = cs; __syncthreads();
    for (int s=256;s>0;s>>=1){ if(t<s) red[t]=fmaxf(red[t],red[t+s]); __syncthreads(); }
    if (t==0) scal[0] = 1.f/(m1*red[0]);
}

// ---------------- pinv iterations, per (b,h) in LDS ----------------
__global__ void pinv_kernel(const float* __restrict__ a2, const float* __restrict__ scal,
                            float* __restrict__ a2i)
{
    int bh = blockIdx.x; int t = threadIdx.x; // 320
    __shared__ float x[289], z[289], xz[289], w1[289], w2[289];
    int i = t/MLM, j = t%MLM;
    bool act = t < MLM*MLM;
    if (act) x[t] = a2[(size_t)bh*MLM*MLM + t];
    __syncthreads();
    if (act) z[t] = x[j*MLM+i] * scal[0];
    __syncthreads();
    for (int it=0; it<6; ++it) {
        if (act){ float a=0.f; for(int k2=0;k2<MLM;++k2) a += x[i*MLM+k2]*z[k2*MLM+j]; xz[t]=a; }
        __syncthreads();
        if (act){ w1[t] = (i==j?7.f:0.f) - xz[t]; }
        __syncthreads();
        if (act){ float a=0.f; for(int k2=0;k2<MLM;++k2) a += xz[i*MLM+k2]*w1[k2*MLM+j]; w2[t]=a; }
        __syncthreads();
        if (act){ w1[t] = (i==j?15.f:0.f) - w2[t]; }
        __syncthreads();
        if (act){ float a=0.f; for(int k2=0;k2<MLM;++k2) a += xz[i*MLM+k2]*w1[k2*MLM+j]; w2[t]=a; }
        __syncthreads();
        if (act){ w1[t] = (i==j?13.f:0.f) - w2[t]; }
        __syncthreads();
        if (act){ float a=0.f; for(int k2=0;k2<MLM;++k2) a += z[i*MLM+k2]*w1[k2*MLM+j]; w2[t]=0.25f*a; }
        __syncthreads();
        if (act) z[t] = w2[t];
        __syncthreads();
    }
    if (act) a2i[(size_t)bh*MLM*MLM + t] = z[t];
}

// ---------------- left = a1 @ a2i ----------------
__global__ void left_kernel(const float* __restrict__ a1, const float* __restrict__ a2i,
                            float* __restrict__ left)
{
    int bh = blockIdx.z*NH + blockIdx.y;
    __shared__ float zi[289];
    int t = threadIdx.x; // 256
    for (int u=t; u<289; u+=256) zi[u] = a2i[(size_t)bh*289+u];
    __syncthreads();
    int e = blockIdx.x*256 + t;
    if (e < NPAD*MLM) {
        int i = e/MLM, j = e%MLM;
        const float* ar = &a1[((size_t)bh*NPAD + i)*MLM];
        float acc=0.f;
        for (int k2=0;k2<MLM;++k2) acc += ar[k2]*zi[k2*MLM+j];
        left[((size_t)bh*NPAD+i)*MLM + j] = acc;
    }
}

// ---------------- a3v = a3 @ v ----------------
__global__ void a3v_kernel(const float* __restrict__ a3, const float* __restrict__ v,
                           float* __restrict__ a3v)
{
    int m = blockIdx.x, h = blockIdx.y, b = blockIdx.z, d = threadIdx.x; // 64
    int bh = b*NH + h;
    const float* ar = &a3[((size_t)bh*MLM+m)*NPAD];
    const float* vb = &v[(size_t)bh*NPAD*DHD + d];
    float acc = 0.f;
    for (int j=0;j<NPAD;++j) acc += ar[j]*vb[(size_t)j*DHD];
    a3v[((size_t)bh*MLM+m)*DHD + d] = acc;
}

// ---------------- headout = left @ a3v + depthwise res conv(v) -> hi/lo halves granule-major ----------------
__global__ void headout_kernel(const float* __restrict__ left, const float* __restrict__ a3v,
                               const float* __restrict__ v, const float* __restrict__ res_w,
                               _Float16* __restrict__ hh, _Float16* __restrict__ hl)
{
    int i = blockIdx.x, h = blockIdx.y, b = blockIdx.z, t = threadIdx.x; // 64
    int bh = b*NH + h;
    __shared__ float lrow[MLM];
    __shared__ float rw[33];
    if (t < MLM) lrow[t] = left[((size_t)bh*NPAD+i)*MLM+t];
    if (t < 33)  rw[t] = res_w[h*33 + t];
    __syncthreads();
    float acc = 0.f;
    for (int m2=0;m2<MLM;++m2) acc += lrow[m2]*a3v[((size_t)bh*MLM+m2)*DHD+t];
    for (int s=0;s<33;++s) {
        int ii = i + s - 16;
        if (ii >= 0 && ii < NPAD) acc += rw[s]*v[((size_t)bh*NPAD+ii)*DHD+t];
    }
    store_hl(hh, hl, h*DHD + t, b*NPAD + i, acc);
}

// ---------------- attn map write: aw = left @ a3, tiled (64 i x 512 j per block) ----------------
__global__ __launch_bounds__(256) void attn_out_kernel(const float* __restrict__ left,
                                                       const float* __restrict__ a3,
                                                       float* __restrict__ aw)
{
    int bh = blockIdx.z; int i0 = blockIdx.y*64; int j0 = blockIdx.x*512;
    int t = threadIdx.x;
    __shared__ float lrows[64][20];   // padded leading dim (80B, 16B-aligned rows)
    for (int u = t; u < 64*MLM; u += 256) {
        int ii = u / MLM, kk = u % MLM;
        int gi = i0 + ii;
        lrows[ii][kk] = (gi < NPAD) ? left[((size_t)bh*NPAD + gi)*MLM + kk] : 0.f;
    }
    __syncthreads();
    int j1 = j0 + t, j2 = j0 + 256 + t;
    float c1[MLM], c2[MLM];
    #pragma unroll
    for (int kk = 0; kk < MLM; ++kk) {
        c1[kk] = (j1 < NPAD) ? a3[((size_t)bh*MLM + kk)*NPAD + j1] : 0.f;
        c2[kk] = (j2 < NPAD) ? a3[((size_t)bh*MLM + kk)*NPAD + j2] : 0.f;
    }
    int imax = NPAD - i0; if (imax > 64) imax = 64;
    for (int ii = 0; ii < imax; ++ii) {
        float lv[17];
        *(float4*)&lv[0]  = *(const float4*)&lrows[ii][0];
        *(float4*)&lv[4]  = *(const float4*)&lrows[ii][4];
        *(float4*)&lv[8]  = *(const float4*)&lrows[ii][8];
        *(float4*)&lv[12] = *(const float4*)&lrows[ii][12];
        lv[16] = lrows[ii][16];
        float s1 = 0.f, s2 = 0.f;
        #pragma unroll
        for (int kk = 0; kk < MLM; ++kk) { s1 += lv[kk]*c1[kk]; s2 += lv[kk]*c2[kk]; }
        size_t ob = ((size_t)bh*NPAD + (i0+ii))*NPAD;
        if (j1 < NPAD) aw[ob + j1] = s1;
        if (j2 < NPAD) aw[ob + j2] = s2;
    }
}

// ---------------- h += proj rows 8.. (residual add) ----------------
__global__ void add_res_kernel(float* __restrict__ h, const float* __restrict__ proj)
{
    size_t e = (size_t)blockIdx.x*256 + threadIdx.x;
    if (e >= (size_t)BATCH*SEQ*DIMC) return;
    int c = e % DIMC; size_t r = e / DIMC;
    int tt = r % SEQ; int b = r / SEQ;
    h[e] += proj[((size_t)(b*NPAD + PAD0 + tt))*DIMC + c];
}

// ---------------- PPEG: transpose to image ----------------
__global__ void ppeg_im_kernel(const float* __restrict__ h, float* __restrict__ im)
{
    size_t e = (size_t)blockIdx.x*256 + threadIdx.x;
    if (e >= (size_t)BATCH*DIMC*NPIX) return;
    int p = e % NPIX; size_t r = e / NPIX;
    int c = r % DIMC; int b = r / DIMC;
    im[e] = h[((size_t)(b*SEQ) + 1 + p)*DIMC + c];
}

// ---------------- PPEG: 7/5/3 depthwise convs + identity, write back to h ----------------
__global__ void ppeg_conv_kernel(const float* __restrict__ im,
                                 const float* __restrict__ w7, const float* __restrict__ b7,
                                 const float* __restrict__ w5, const float* __restrict__ b5,
                                 const float* __restrict__ w3, const float* __restrict__ b3,
                                 float* __restrict__ h)
{
    int c = blockIdx.x; int b = blockIdx.y; int t = threadIdx.x; // 256
    __shared__ float img[NPIX];
    __shared__ float wf[49+25+9];
    const float* src = &im[((size_t)(b*DIMC+c))*NPIX];
    for (int p=t; p<NPIX; p+=256) img[p] = src[p];
    if (t < 49) wf[t] = w7[c*49+t];
    else if (t >= 64 && t < 64+25) wf[49 + (t-64)] = w5[c*25 + (t-64)];
    else if (t >= 96 && t < 96+9)  wf[74 + (t-96)] = w3[c*9 + (t-96)];
    __syncthreads();
    float bias = b7[c] + b5[c] + b3[c];
    for (int p=t; p<NPIX; p+=256) {
        int y = p/HS, x = p%HS;
        float acc = img[p] + bias;
        for (int dy=-3; dy<=3; ++dy){ int yy=y+dy; if (yy<0||yy>=HS) continue;
            for (int dx=-3; dx<=3; ++dx){ int xx=x+dx; if (xx<0||xx>=HS) continue;
                acc += wf[(dy+3)*7+(dx+3)]*img[yy*HS+xx]; } }
        for (int dy=-2; dy<=2; ++dy){ int yy=y+dy; if (yy<0||yy>=HS) continue;
            for (int dx=-2; dx<=2; ++dx){ int xx=x+dx; if (xx<0||xx>=HS) continue;
                acc += wf[49+(dy+2)*5+(dx+2)]*img[yy*HS+xx]; } }
        for (int dy=-1; dy<=1; ++dy){ int yy=y+dy; if (yy<0||yy>=HS) continue;
            for (int dx=-1; dx<=1; ++dx){ int xx=x+dx; if (xx<0||xx>=HS) continue;
                acc += wf[74+(dy+1)*3+(dx+1)]*img[yy*HS+xx]; } }
        h[((size_t)(b*SEQ)+1+p)*DIMC + c] = acc;
    }
}

// ---------------- final: LN(cls row) @ fc2 + bias -> logits ----------------
__global__ void final_kernel(const float* __restrict__ h, const float* __restrict__ g,
                             const float* __restrict__ bta, const float* __restrict__ fc2w,
                             const float* __restrict__ fc2b, float* __restrict__ out)
{
    int b = blockIdx.x; int t = threadIdx.x; // 512
    __shared__ float red[512];
    const float* x = &h[(size_t)b*SEQ*DIMC];
    float xv = x[t];
    red[t] = xv; __syncthreads();
    for (int s=256;s>0;s>>=1){ if(t<s) red[t]+=red[t+s]; __syncthreads(); }
    float mu = red[0]/512.f; __syncthreads();
    float d = xv - mu;
    red[t] = d*d; __syncthreads();
    for (int s=256;s>0;s>>=1){ if(t<s) red[t]+=red[t+s]; __syncthreads(); }
    float var = red[0]/512.f; __syncthreads();
    float hn = d * (1.f/sqrtf(var+1e-5f)) * g[t] + bta[t];
    for (int c=0;c<2;++c) {
        red[t] = hn * fc2w[t*2+c]; __syncthreads();
        for (int s=256;s>0;s>>=1){ if(t<s) red[t]+=red[t+s]; __syncthreads(); }
        if (t==0) out[b*2+c] = red[0] + fc2b[c];
        __syncthreads();
    }
}

// ================= host =================
extern "C" void kernel_launch(void* const* d_in, const int* in_sizes, int n_in,
                              void* d_out, int out_size, void* d_ws, size_t ws_size,
                              hipStream_t stream)
{
    (void)in_sizes; (void)n_in; (void)out_size; (void)ws_size;
    const float* feats = (const float*)d_in[0];
    const float* fc1_w = (const float*)d_in[1];
    const float* fc1_b = (const float*)d_in[2];
    const float* cls   = (const float*)d_in[3];
    const float* ln_g[2]  = {(const float*)d_in[4],  (const float*)d_in[10]};
    const float* ln_b[2]  = {(const float*)d_in[5],  (const float*)d_in[11]};
    const float* qkv_w[2] = {(const float*)d_in[6],  (const float*)d_in[12]};
    const float* out_w[2] = {(const float*)d_in[7],  (const float*)d_in[13]};
    const float* out_b[2] = {(const float*)d_in[8],  (const float*)d_in[14]};
    const float* res_w[2] = {(const float*)d_in[9],  (const float*)d_in[15]};
    const float* w7 = (const float*)d_in[16]; const float* b7 = (const float*)d_in[17];
    const float* w5 = (const float*)d_in[18]; const float* b5 = (const float*)d_in[19];
    const float* w3 = (const float*)d_in[20]; const float* b3 = (const float*)d_in[21];
    const float* ng = (const float*)d_in[22]; const float* nb = (const float*)d_in[23];
    const float* fc2w = (const float*)d_in[24]; const float* fc2b = (const float*)d_in[25];

    float* ws = (float*)d_ws;
    size_t off = 0;
    float* h    = ws + off; off += (size_t)BATCH*SEQ*DIMC;      // 2,167,808
    float* h0   = ws + off; off += (size_t)BATCH*NSEQ*DIMC;     // 2,097,152
    float* qkv  = ws + off; off += (size_t)BATCH*NPAD*1536;     // 6,528,000 (aliased below)
    float* q    = ws + off; off += (size_t)BATCH*NH*NPAD*DHD;
    float* k    = ws + off; off += (size_t)BATCH*NH*NPAD*DHD;
    float* v    = ws + off; off += (size_t)BATCH*NH*NPAD*DHD;
    float* ql   = ws + off; off += (size_t)BATCH*NH*MLM*DHD;
    float* kl   = ws + off; off += (size_t)BATCH*NH*MLM*DHD;
    float* a1   = ws + off; off += (size_t)BATCH*NH*NPAD*MLM;
    float* a2   = ws + off; off += (size_t)BATCH*NH*MLM*MLM;
    float* a2i  = ws + off; off += (size_t)BATCH*NH*MLM*MLM;
    float* scal = ws + off; off += 16;
    float* a3   = ws + off; off += (size_t)BATCH*NH*MLM*NPAD;
    float* left = ws + off; off += (size_t)BATCH*NH*NPAD*MLM;
    float* a3v  = ws + off; off += (size_t)BATCH*NH*MLM*DHD;
    // half-precision hi/lo staging buffers (granule-major). Max A: 4096x1024 halves.
    _Float16* XAh = (_Float16*)(ws + off); off += 2097152;   // 4,194,304 halves
    _Float16* XAl = (_Float16*)(ws + off); off += 2097152;
    _Float16* WBh = (_Float16*)(ws + off); off += 393216;    // 786,432 halves (max 1536x512)
    _Float16* WBl = (_Float16*)(ws + off); off += 393216;
    // aliases into dead qkv buffer (qkv fp32 dead after split_heads)
    float* proj = qkv;                               // 2,176,000
    float* im   = qkv + (size_t)BATCH*NPAD*DIMC;     // 2,166,784 (fits in 6,528,000)

    float* outp = (float*)d_out;

    // FC1 + relu -> h0  (f16x3 MFMA)
    convA_kernel<<<((size_t)4096*128+255)/256, 256, 0, stream>>>(feats, XAh, XAl, 4096, NIN);
    convB_kernel<<<((size_t)512*128+255)/256, 256, 0, stream>>>(fc1_w, WBh, WBl, DIMC, NIN);
    gemm_mfma<<<dim3(DIMC/128, 4096/128), 256, 0, stream>>>(
        XAh, XAl, WBh, WBl, fc1_b, h0, BATCH*NSEQ, DIMC, NIN, 1);
    // build h
    {
        size_t tot = (size_t)BATCH*SEQ*DIMC;
        buildh_kernel<<<(tot+255)/256, 256, 0, stream>>>(h0, cls, h);
    }

    for (int L = 0; L < 2; ++L) {
        float* aw = outp + 4 + (size_t)L*AWSZ;
        // LN -> hi/lo halves (padded rows zeroed), granule-major
        ln_pad_kernel<<<dim3(NPAD, BATCH), 256, 0, stream>>>(h, ln_g[L], ln_b[L], XAh, XAl);
        // qkv = xp @ qkv_w  (f16x3 MFMA)
        convB_kernel<<<((size_t)1536*64+255)/256, 256, 0, stream>>>(qkv_w[L], WBh, WBl, 1536, DIMC);
        gemm_mfma<<<dim3(1536/128, (RA+127)/128), 256, 0, stream>>>(
            XAh, XAl, WBh, WBl, nullptr, qkv, RA, 1536, DIMC, 0);
        // split heads
        {
            size_t tot = (size_t)BATCH*NH*NPAD*DHD;
            split_heads_kernel<<<(tot+255)/256, 256, 0, stream>>>(qkv, q, k, v);
        }
        landmark_kernel<<<dim3(MLM, NH, BATCH), 64, 0, stream>>>(q, k, ql, kl);
        a1_kernel<<<dim3(NPAD, NH, BATCH), 64, 0, stream>>>(q, kl, a1);
        a2_kernel<<<dim3(BATCH*NH), 320, 0, stream>>>(ql, kl, a2);
        a3_kernel<<<dim3(MLM, NH, BATCH), 256, 0, stream>>>(ql, k, a3);
        pinv_scale_kernel<<<1, 512, 0, stream>>>(a2, scal);
        pinv_kernel<<<BATCH*NH, 320, 0, stream>>>(a2, scal, a2i);
        left_kernel<<<dim3((NPAD*MLM+255)/256, NH, BATCH), 256, 0, stream>>>(a1, a2i, left);
        a3v_kernel<<<dim3(MLM, NH, BATCH), 64, 0, stream>>>(a3, v, a3v);
        // headout writes hi/lo halves directly (A operand of proj GEMM)
        headout_kernel<<<dim3(NPAD, NH, BATCH), 64, 0, stream>>>(left, a3v, v, res_w[L], XAh, XAl);
        attn_out_kernel<<<dim3((NPAD+511)/512, (NPAD+63)/64, BATCH*NH), 256, 0, stream>>>(left, a3, aw);
        // proj = hout @ out_w + out_b  (f16x3 MFMA)
        convB_kernel<<<((size_t)512*64+255)/256, 256, 0, stream>>>(out_w[L], WBh, WBl, DIMC, DIMC);
        gemm_mfma<<<dim3(DIMC/128, (RA+127)/128), 256, 0, stream>>>(
            XAh, XAl, WBh, WBl, out_b[L], proj, RA, DIMC, DIMC, 0);
        // h += proj[rows 8..]
        {
            size_t tot = (size_t)BATCH*SEQ*DIMC;
            add_res_kernel<<<(tot+255)/256, 256, 0, stream>>>(h, proj);
        }
        if (L == 0) {
            // PPEG
            size_t tot = (size_t)BATCH*DIMC*NPIX;
            ppeg_im_kernel<<<(tot+255)/256, 256, 0, stream>>>(h, im);
            ppeg_conv_kernel<<<dim3(DIMC, BATCH), 256, 0, stream>>>(im, w7, b7, w5, b5, w3, b3, h);
        }
    }
    final_kernel<<<BATCH, 512, 0, stream>>>(h, ng, nb, fc2w, fc2b, outp);
}

// Round 2
// 1363.954 us; speedup vs baseline: 1.5638x; 1.0297x over previous
//
#include <hip/hip_runtime.h>
#include <math.h>
#include <stdint.h>

// ---------------- constants ----------------
#define BATCH 2
#define NIN   1024
#define NSEQ  2048
#define DIMC  512
#define NH    8
#define DHD   64
#define MLM   17
#define LBLK  125
#define SEQ   2117      // 1 + 2116
#define NPAD  2125      // SEQ + 8
#define PAD0  8
#define HS    46
#define NPIX  2116      // 46*46
#define RA    4250      // BATCH*NPAD rows of the stacked activation matrices
#define AWSZ  ((size_t)BATCH*NH*NPAD*NPAD)   // 72,250,000

typedef _Float16 half8 __attribute__((ext_vector_type(8)));
typedef float    floatx4 __attribute__((ext_vector_type(4)));

// write one fp32 value as hi/lo _Float16 pair in granule-major layout [k/8][row][8]
__device__ __forceinline__ void store_hl(_Float16* __restrict__ xh, _Float16* __restrict__ xl,
                                         int c, int ra, float v)
{
    _Float16 hv = (_Float16)v;
    size_t o = ((size_t)(c >> 3) * RA + ra) * 8 + (c & 7);
    xh[o] = hv;
    xl[o] = (_Float16)(v - (float)hv);
}

// ---------------- conversion: A fp32 [R][K] -> granule-major hi/lo halves ----------------
__global__ void convA_kernel(const float* __restrict__ X, _Float16* __restrict__ hi,
                             _Float16* __restrict__ lo, int R, int K)
{
    int GK = K >> 3;
    size_t idx = (size_t)blockIdx.x * 256 + threadIdx.x;
    if (idx >= (size_t)R * GK) return;
    int r = (int)(idx % R); int gk = (int)(idx / R);
    const float* s = X + (size_t)r * K + gk * 8;
    half8 h, l;
    #pragma unroll
    for (int j = 0; j < 8; ++j) {
        float x = s[j];
        _Float16 hh = (_Float16)x;
        h[j] = hh;
        l[j] = (_Float16)(x - (float)hh);
    }
    *(half8*)(hi + idx * 8) = h;   // offset == ((size_t)gk*R + r)*8
    *(half8*)(lo + idx * 8) = l;
}

// ---------------- conversion: B fp32 [K][N] -> B^T granule-major hi/lo halves ----------------
__global__ void convB_kernel(const float* __restrict__ X, _Float16* __restrict__ hi,
                             _Float16* __restrict__ lo, int N, int K)
{
    int GK = K >> 3;
    size_t idx = (size_t)blockIdx.x * 256 + threadIdx.x;
    if (idx >= (size_t)N * GK) return;
    int n = (int)(idx % N); int gk = (int)(idx / N);
    const float* s = X + (size_t)(gk * 8) * N + n;
    half8 h, l;
    #pragma unroll
    for (int j = 0; j < 8; ++j) {
        float x = s[(size_t)j * N];
        _Float16 hh = (_Float16)x;
        h[j] = hh;
        l[j] = (_Float16)(x - (float)hh);
    }
    *(half8*)(hi + idx * 8) = h;
    *(half8*)(lo + idx * 8) = l;
}

// ---------------- MFMA GEMM, f16x3 split, 2-phase double-buffered staging ----------------
// A,B supplied as granule-major hi/lo halves: A[k/8][m][8], B^T[k/8][n][8].
// 128x128 tile, 4 waves each 64x64, K-step 32, 16x16x32_f16 MFMA.
// split==0: C = A@B (+bias)(+relu). split==1: scatter into q(x0.125)/k/v head-major.
__global__ __launch_bounds__(256) void gemm_mfma(
    const _Float16* __restrict__ Ah, const _Float16* __restrict__ Al,
    const _Float16* __restrict__ Bh, const _Float16* __restrict__ Bl,
    const float* __restrict__ bias, float* __restrict__ C,
    int Mn, int Nn, int Kn, int relu,
    int split, float* __restrict__ qp, float* __restrict__ kp, float* __restrict__ vp)
{
    __shared__ _Float16 sA[2][2][4][128][8];   // [buf][hi/lo][granule][row][8] = 32 KB
    __shared__ _Float16 sB[2][2][4][128][8];   // 32 KB
    const int tid = threadIdx.x;
    const int wv = tid >> 6, ln = tid & 63;
    const int m0 = blockIdx.y * 128, n0 = blockIdx.x * 128;
    const int wm = (wv >> 1) * 64, wn = (wv & 1) * 64;
    const int g = ln >> 4, rr = ln & 15;

    floatx4 acc[4][4];
    #pragma unroll
    for (int m = 0; m < 4; ++m)
        #pragma unroll
        for (int n = 0; n < 4; ++n)
            acc[m][n] = (floatx4){0.f, 0.f, 0.f, 0.f};

    auto STAGE = [&](int bf, int gk0) {
        #pragma unroll
        for (int q2 = 0; q2 < 8; ++q2) {
            int c = wv + q2 * 4;
            int arr = c >> 3, gg = (c >> 1) & 3, hf = c & 1;
            const _Float16* base = (arr == 0) ? Ah : (arr == 1) ? Al : (arr == 2) ? Bh : Bl;
            int Rdim = (arr < 2) ? Mn : Nn;
            int rg = ((arr < 2) ? m0 : n0) + hf * 64 + ln;
            if (arr < 2 && rg >= Mn) rg = Mn - 1;   // clamp tail rows (stores are guarded)
            const _Float16* src = base + ((size_t)(gk0 + gg) * Rdim + rg) * 8;
            _Float16* dst = (arr == 0) ? &sA[bf][0][gg][hf * 64][0] :
                            (arr == 1) ? &sA[bf][1][gg][hf * 64][0] :
                            (arr == 2) ? &sB[bf][0][gg][hf * 64][0] :
                                         &sB[bf][1][gg][hf * 64][0];
            __builtin_amdgcn_global_load_lds(
                (__attribute__((address_space(1))) void*)(uintptr_t)src,
                (__attribute__((address_space(3))) void*)dst, 16, 0, 0);
        }
    };

    const int nt = Kn >> 5;
    STAGE(0, 0);
    __syncthreads();
    for (int t = 0; t < nt; ++t) {
        const int cur = t & 1;
        if (t + 1 < nt) STAGE(cur ^ 1, (t + 1) * 4);   // prefetch issued BEFORE compute
        half8 a_h[4], a_l[4], b_h[4], b_l[4];
        #pragma unroll
        for (int m = 0; m < 4; ++m) {
            a_h[m] = *(const half8*)&sA[cur][0][g][wm + m * 16 + rr][0];
            a_l[m] = *(const half8*)&sA[cur][1][g][wm + m * 16 + rr][0];
        }
        #pragma unroll
        for (int n = 0; n < 4; ++n) {
            b_h[n] = *(const half8*)&sB[cur][0][g][wn + n * 16 + rr][0];
            b_l[n] = *(const half8*)&sB[cur][1][g][wn + n * 16 + rr][0];
        }
        #pragma unroll
        for (int m = 0; m < 4; ++m)
            #pragma unroll
            for (int n = 0; n < 4; ++n) {
                acc[m][n] = __builtin_amdgcn_mfma_f32_16x16x32_f16(a_h[m], b_h[n], acc[m][n], 0, 0, 0);
                acc[m][n] = __builtin_amdgcn_mfma_f32_16x16x32_f16(a_l[m], b_h[n], acc[m][n], 0, 0, 0);
                acc[m][n] = __builtin_amdgcn_mfma_f32_16x16x32_f16(a_h[m], b_l[n], acc[m][n], 0, 0, 0);
            }
        __syncthreads();   // one barrier per K-step: drains prefetch + protects both buffers
    }

    // epilogue: C/D layout col = lane&15, row = (lane>>4)*4 + r
    const int rq = ln >> 4;
    if (!split) {
        #pragma unroll
        for (int n = 0; n < 4; ++n) {
            int col = n0 + wn + n * 16 + rr;
            float bv = bias ? bias[col] : 0.f;
            #pragma unroll
            for (int m = 0; m < 4; ++m) {
                #pragma unroll
                for (int r = 0; r < 4; ++r) {
                    int row = m0 + wm + m * 16 + rq * 4 + r;
                    if (row < Mn) {
                        float vv = acc[m][n][r] + bv;
                        if (relu) vv = fmaxf(vv, 0.f);
                        C[(size_t)row * Nn + col] = vv;
                    }
                }
            }
        }
    } else {
        // qkv split: col in [0,1536): sect=col>>9 (q/k/v), head=(col>>6)&7, d=col&63
        #pragma unroll
        for (int n = 0; n < 4; ++n) {
            int col = n0 + wn + n * 16 + rr;
            int sect = col >> 9, hh = (col >> 6) & 7, dd = col & 63;
            float* dstb = (sect == 0) ? qp : (sect == 1) ? kp : vp;
            float sc = (sect == 0) ? 0.125f : 1.f;
            #pragma unroll
            for (int m = 0; m < 4; ++m) {
                #pragma unroll
                for (int r = 0; r < 4; ++r) {
                    int row = m0 + wm + m * 16 + rq * 4 + r;
                    if (row < Mn) {
                        int b = (row >= NPAD) ? 1 : 0;
                        int i = row - b * NPAD;
                        dstb[(((size_t)(b * NH + hh)) * NPAD + i) * DHD + dd] = acc[m][n][r] * sc;
                    }
                }
            }
        }
    }
}

// ---------------- build h: cls + fc1out + wrap (float4) ----------------
__global__ void buildh_kernel(const float* __restrict__ h0, const float* __restrict__ cls,
                              float* __restrict__ h)
{
    size_t e4 = (size_t)blockIdx.x*256 + threadIdx.x;
    if (e4 >= (size_t)BATCH*SEQ*DIMC/4) return;
    int c4 = (int)(e4 % (DIMC/4)); size_t r = e4 / (DIMC/4);
    int t = (int)(r % SEQ); int b = (int)(r / SEQ);
    float4 val;
    if (t == 0) val = ((const float4*)cls)[c4];
    else {
        int n = t - 1;
        if (n >= NSEQ) n -= NSEQ;
        val = ((const float4*)h0)[((size_t)(b*NSEQ + n))*(DIMC/4) + c4];
    }
    ((float4*)h)[e4] = val;
}

// ---------------- LayerNorm rows of h -> granule-major hi/lo halves (rows 0..7 zero) ----------------
__global__ void ln_pad_kernel(const float* __restrict__ h, const float* __restrict__ g,
                              const float* __restrict__ bta,
                              _Float16* __restrict__ xh, _Float16* __restrict__ xl)
{
    int r = blockIdx.x; int b = blockIdx.y; int t = threadIdx.x; // block 256
    int ra = b*NPAD + r;
    if (r < PAD0) {
        store_hl(xh, xl, t, ra, 0.f);
        store_hl(xh, xl, t + 256, ra, 0.f);
        return;
    }
    const float* x = &h[((size_t)(b*SEQ + r-PAD0))*DIMC];
    __shared__ float ws[4];
    int wid = t >> 6, ln = t & 63;
    float x0 = x[t], x1 = x[t+256];
    float s = x0 + x1;
    #pragma unroll
    for (int m = 1; m < 64; m <<= 1) s += __shfl_xor(s, m, 64);
    if (ln == 0) ws[wid] = s;
    __syncthreads();
    float mu = (ws[0]+ws[1]+ws[2]+ws[3]) * (1.f/512.f);
    float d0 = x0-mu, d1 = x1-mu;
    float vv = d0*d0 + d1*d1;
    #pragma unroll
    for (int m = 1; m < 64; m <<= 1) vv += __shfl_xor(vv, m, 64);
    __syncthreads();
    if (ln == 0) ws[wid] = vv;
    __syncthreads();
    float rstd = 1.0f / sqrtf((ws[0]+ws[1]+ws[2]+ws[3])*(1.f/512.f) + 1e-5f);
    store_hl(xh, xl, t,       ra, d0*rstd*g[t]     + bta[t]);
    store_hl(xh, xl, t + 256, ra, d1*rstd*g[t+256] + bta[t+256]);
}

// ---------------- landmarks: mean over 125-blocks ----------------
__global__ void landmark_kernel(const float* __restrict__ q, const float* __restrict__ k,
                                float* __restrict__ ql, float* __restrict__ kl)
{
    int m = blockIdx.x, h = blockIdx.y, b = blockIdx.z, d = threadIdx.x; // 64 thr
    int bh = b*NH + h;
    size_t base = ((size_t)bh*NPAD + m*LBLK)*DHD + d;
    float sq = 0.f, sk = 0.f;
    for (int r=0;r<LBLK;++r){ sq += q[base + (size_t)r*DHD]; sk += k[base + (size_t)r*DHD]; }
    size_t o = ((size_t)bh*MLM + m)*DHD + d;
    ql[o] = sq / 125.f; kl[o] = sk / 125.f;
}

// ---------------- fused: a1 row softmax(q@kl^T) then left = a1row @ a2i ----------------
__global__ void a1_left_kernel(const float* __restrict__ q, const float* __restrict__ kl,
                               const float* __restrict__ a2i, float* __restrict__ left)
{
    int i = blockIdx.x, h = blockIdx.y, b = blockIdx.z;
    int bh = b*NH + h; int lane = threadIdx.x; // 64
    __shared__ alignas(16) float qrow[64];
    __shared__ float dots[MLM];
    __shared__ float arow[MLM];
    qrow[lane] = q[((size_t)bh*NPAD + i)*DHD + lane];
    __syncthreads();
    if (lane < MLM) {
        const float4* kr4 = (const float4*)&kl[((size_t)bh*MLM + lane)*DHD];
        const float4* q4 = (const float4*)qrow;
        float acc = 0.f;
        #pragma unroll
        for (int d4=0; d4<16; ++d4) {
            float4 a = q4[d4], bb = kr4[d4];
            acc += a.x*bb.x + a.y*bb.y + a.z*bb.z + a.w*bb.w;
        }
        dots[lane] = acc;
    }
    __syncthreads();
    if (lane < MLM) {
        float mx = -1e30f;
        for (int u=0;u<MLM;++u) mx = fmaxf(mx, dots[u]);
        float s = 0.f;
        for (int u=0;u<MLM;++u) s += expf(dots[u]-mx);
        arow[lane] = expf(dots[lane]-mx)/s;
    }
    __syncthreads();
    if (lane < MLM) {
        const float* zi = &a2i[(size_t)bh*MLM*MLM];
        float acc = 0.f;
        for (int k2=0;k2<MLM;++k2) acc += arow[k2]*zi[k2*MLM + lane];
        left[((size_t)bh*NPAD + i)*MLM + lane] = acc;
    }
}

// ---------------- a2 = softmax(ql @ kl^T), 17x17 per (b,h) ----------------
__global__ void a2_kernel(const float* __restrict__ ql, const float* __restrict__ kl,
                          float* __restrict__ a2)
{
    int bh = blockIdx.x; int t = threadIdx.x; // 320
    __shared__ float s[MLM*MLM];
    if (t < MLM*MLM) {
        int m = t/MLM, j = t%MLM;
        const float* qr = &ql[((size_t)bh*MLM+m)*DHD];
        const float* kr = &kl[((size_t)bh*MLM+j)*DHD];
        float acc=0.f; for(int d=0;d<DHD;++d) acc += qr[d]*kr[d];
        s[t] = acc;
    }
    __syncthreads();
    if (t < MLM*MLM) {
        int m = t/MLM;
        float mx=-1e30f; for(int u=0;u<MLM;++u) mx=fmaxf(mx, s[m*MLM+u]);
        float sm=0.f; for(int u=0;u<MLM;++u) sm += expf(s[m*MLM+u]-mx);
        a2[(size_t)bh*MLM*MLM + t] = expf(s[t]-mx)/sm;
    }
}

// ---------------- a3 = softmax(ql @ k^T), rows of 2125 ----------------
__global__ void a3_kernel(const float* __restrict__ ql, const float* __restrict__ k,
                          float* __restrict__ a3)
{
    int m = blockIdx.x, h = blockIdx.y, b = blockIdx.z;
    int bh = b*NH + h; int tid = threadIdx.x; // 256
    __shared__ alignas(16) float qlrow[64];
    __shared__ float buf[NPAD];
    __shared__ float red[256];
    if (tid < 64) qlrow[tid] = ql[((size_t)bh*MLM+m)*DHD + tid];
    __syncthreads();
    for (int j = tid; j < NPAD; j += 256) {
        const float4* kr4 = (const float4*)&k[((size_t)bh*NPAD + j)*DHD];
        const float4* q4 = (const float4*)qlrow;
        float acc = 0.f;
        #pragma unroll
        for (int d4=0; d4<16; ++d4) {
            float4 kk = kr4[d4], qq = q4[d4];
            acc += qq.x*kk.x + qq.y*kk.y + qq.z*kk.z + qq.w*kk.w;
        }
        buf[j] = acc;
    }
    __syncthreads();
    float mx = -1e30f;
    for (int j = tid; j < NPAD; j += 256) mx = fmaxf(mx, buf[j]);
    red[tid] = mx; __syncthreads();
    for (int s=128;s>0;s>>=1){ if(tid<s) red[tid]=fmaxf(red[tid],red[tid+s]); __syncthreads(); }
    mx = red[0]; __syncthreads();
    float sm = 0.f;
    for (int j = tid; j < NPAD; j += 256) sm += expf(buf[j]-mx);
    red[tid] = sm; __syncthreads();
    for (int s=128;s>0;s>>=1){ if(tid<s) red[tid]+=red[tid+s]; __syncthreads(); }
    sm = red[0];
    for (int j = tid; j < NPAD; j += 256)
        a3[((size_t)bh*MLM+m)*NPAD + j] = expf(buf[j]-mx)/sm;
}

// ---------------- pinv iterations, per (b,h) in LDS; global scale computed in-block ----------------
__global__ void pinv_kernel(const float* __restrict__ a2, float* __restrict__ a2i)
{
    int bh = blockIdx.x; int t = threadIdx.x; // 320
    __shared__ float x[289], z[289], xz[289], w1[289], w2[289];
    __shared__ float red[320], red2[320];
    // global max row-sum / col-sum over ALL 16 (b,h) matrices (redundant per block, cheap)
    float rs = -1e30f, cs = -1e30f;
    if (t < BATCH*NH*MLM) {
        int m2 = t/MLM, i2 = t%MLM;
        const float* xx = &a2[(size_t)m2*MLM*MLM];
        float r=0.f, c=0.f;
        for (int j=0;j<MLM;++j){ r += fabsf(xx[i2*MLM+j]); c += fabsf(xx[j*MLM+i2]); }
        rs = r; cs = c;
    }
    red[t] = rs; red2[t] = cs; __syncthreads();
    for (int s=256;s>0;s>>=1){
        if (t<s && t+s<320){ red[t]=fmaxf(red[t],red[t+s]); red2[t]=fmaxf(red2[t],red2[t+s]); }
        __syncthreads();
    }
    float scal = 1.f/(red[0]*red2[0]);

    int i = t/MLM, j = t%MLM;
    bool act = t < MLM*MLM;
    if (act) x[t] = a2[(size_t)bh*MLM*MLM + t];
    __syncthreads();
    if (act) z[t] = x[j*MLM+i] * scal;
    __syncthreads();
    for (int it=0; it<6; ++it) {
        if (act){ float a=0.f; for(int k2=0;k2<MLM;++k2) a += x[i*MLM+k2]*z[k2*MLM+j]; xz[t]=a; }
        __syncthreads();
        if (act){ w1[t] = (i==j?7.f:0.f) - xz[t]; }
        __syncthreads();
        if (act){ float a=0.f; for(int k2=0;k2<MLM;++k2) a += xz[i*MLM+k2]*w1[k2*MLM+j]; w2[t]=a; }
        __syncthreads();
        if (act){ w1[t] = (i==j?15.f:0.f) - w2[t]; }
        __syncthreads();
        if (act){ float a=0.f; for(int k2=0;k2<MLM;++k2) a += xz[i*MLM+k2]*w1[k2*MLM+j]; w2[t]=a; }
        __syncthreads();
        if (act){ w1[t] = (i==j?13.f:0.f) - w2[t]; }
        __syncthreads();
        if (act){ float a=0.f; for(int k2=0;k2<MLM;++k2) a += z[i*MLM+k2]*w1[k2*MLM+j]; w2[t]=0.25f*a; }
        __syncthreads();
        if (act) z[t] = w2[t];
        __syncthreads();
    }
    if (act) a2i[(size_t)bh*MLM*MLM + t] = z[t];
}

// ---------------- a3v = a3 @ v ----------------
__global__ void a3v_kernel(const float* __restrict__ a3, const float* __restrict__ v,
                           float* __restrict__ a3v)
{
    int m = blockIdx.x, h = blockIdx.y, b = blockIdx.z, d = threadIdx.x; // 64
    int bh = b*NH + h;
    const float* ar = &a3[((size_t)bh*MLM+m)*NPAD];
    const float* vb = &v[(size_t)bh*NPAD*DHD + d];
    float acc = 0.f;
    for (int j=0;j<NPAD;++j) acc += ar[j]*vb[(size_t)j*DHD];
    a3v[((size_t)bh*MLM+m)*DHD + d] = acc;
}

// ---------------- headout = left @ a3v + depthwise res conv(v) -> hi/lo halves granule-major ----------------
__global__ void headout_kernel(const float* __restrict__ left, const float* __restrict__ a3v,
                               const float* __restrict__ v, const float* __restrict__ res_w,
                               _Float16* __restrict__ hh, _Float16* __restrict__ hl)
{
    int i = blockIdx.x, h = blockIdx.y, b = blockIdx.z, t = threadIdx.x; // 64
    int bh = b*NH + h;
    __shared__ float lrow[MLM];
    __shared__ float rw[33];
    if (t < MLM) lrow[t] = left[((size_t)bh*NPAD+i)*MLM+t];
    if (t < 33)  rw[t] = res_w[h*33 + t];
    __syncthreads();
    float acc = 0.f;
    for (int m2=0;m2<MLM;++m2) acc += lrow[m2]*a3v[((size_t)bh*MLM+m2)*DHD+t];
    for (int s=0;s<33;++s) {
        int ii = i + s - 16;
        if (ii >= 0 && ii < NPAD) acc += rw[s]*v[((size_t)bh*NPAD+ii)*DHD+t];
    }
    store_hl(hh, hl, h*DHD + t, b*NPAD + i, acc);
}

// ---------------- attn map write: aw = left @ a3, tiled (64 i x 512 j per block) ----------------
__global__ __launch_bounds__(256) void attn_out_kernel(const float* __restrict__ left,
                                                       const float* __restrict__ a3,
                                                       float* __restrict__ aw)
{
    int bh = blockIdx.z; int i0 = blockIdx.y*64; int j0 = blockIdx.x*512;
    int t = threadIdx.x;
    __shared__ float lrows[64][20];   // padded leading dim (80B, 16B-aligned rows)
    for (int u = t; u < 64*MLM; u += 256) {
        int ii = u / MLM, kk = u % MLM;
        int gi = i0 + ii;
        lrows[ii][kk] = (gi < NPAD) ? left[((size_t)bh*NPAD + gi)*MLM + kk] : 0.f;
    }
    __syncthreads();
    int j1 = j0 + t, j2 = j0 + 256 + t;
    float c1[MLM], c2[MLM];
    #pragma unroll
    for (int kk = 0; kk < MLM; ++kk) {
        c1[kk] = (j1 < NPAD) ? a3[((size_t)bh*MLM + kk)*NPAD + j1] : 0.f;
        c2[kk] = (j2 < NPAD) ? a3[((size_t)bh*MLM + kk)*NPAD + j2] : 0.f;
    }
    int imax = NPAD - i0; if (imax > 64) imax = 64;
    for (int ii = 0; ii < imax; ++ii) {
        float lv[17];
        *(float4*)&lv[0]  = *(const float4*)&lrows[ii][0];
        *(float4*)&lv[4]  = *(const float4*)&lrows[ii][4];
        *(float4*)&lv[8]  = *(const float4*)&lrows[ii][8];
        *(float4*)&lv[12] = *(const float4*)&lrows[ii][12];
        lv[16] = lrows[ii][16];
        float s1 = 0.f, s2 = 0.f;
        #pragma unroll
        for (int kk = 0; kk < MLM; ++kk) { s1 += lv[kk]*c1[kk]; s2 += lv[kk]*c2[kk]; }
        size_t ob = ((size_t)bh*NPAD + (i0+ii))*NPAD;
        if (j1 < NPAD) aw[ob + j1] = s1;
        if (j2 < NPAD) aw[ob + j2] = s2;
    }
}

// ---------------- h += proj rows 8.. (residual add, float4) ----------------
__global__ void add_res_kernel(float* __restrict__ h, const float* __restrict__ proj)
{
    size_t e4 = (size_t)blockIdx.x*256 + threadIdx.x;
    if (e4 >= (size_t)BATCH*SEQ*DIMC/4) return;
    int c4 = (int)(e4 % (DIMC/4)); size_t r = e4 / (DIMC/4);
    int tt = (int)(r % SEQ); int b = (int)(r / SEQ);
    float4 p = ((const float4*)proj)[((size_t)(b*NPAD + PAD0 + tt))*(DIMC/4) + c4];
    float4* hp = &((float4*)h)[e4];
    float4 hv = *hp;
    hv.x += p.x; hv.y += p.y; hv.z += p.z; hv.w += p.w;
    *hp = hv;
}

// ---------------- PPEG: LDS-tiled transpose h(tokens x chan) -> im[b][c][p] ----------------
__global__ void transpose_h2im(const float* __restrict__ h, float* __restrict__ im)
{
    __shared__ float tile[32][33];
    int p0 = blockIdx.x*32, c0 = blockIdx.y*32, b = blockIdx.z;
    int tx = threadIdx.x & 31, ty = threadIdx.x >> 5; // 32x8
    #pragma unroll
    for (int i=0;i<32;i+=8) {
        int p = p0 + ty + i;
        if (p < NPIX) tile[ty+i][tx] = h[((size_t)(b*SEQ) + 1 + p)*DIMC + c0 + tx];
    }
    __syncthreads();
    #pragma unroll
    for (int i=0;i<32;i+=8) {
        int c = c0 + ty + i, p = p0 + tx;
        if (p < NPIX) im[((size_t)(b*DIMC) + c)*NPIX + p] = tile[tx][ty+i];
    }
}

// ---------------- PPEG: 7/5/3 depthwise convs + identity, channel-major in/out ----------------
__global__ void ppeg_conv_kernel(const float* __restrict__ im,
                                 const float* __restrict__ w7, const float* __restrict__ b7,
                                 const float* __restrict__ w5, const float* __restrict__ b5,
                                 const float* __restrict__ w3, const float* __restrict__ b3,
                                 float* __restrict__ im2)
{
    int c = blockIdx.x; int b = blockIdx.y; int t = threadIdx.x; // 256
    __shared__ float img[NPIX];
    __shared__ float wf[49+25+9];
    const float* src = &im[((size_t)(b*DIMC+c))*NPIX];
    for (int p=t; p<NPIX; p+=256) img[p] = src[p];
    if (t < 49) wf[t] = w7[c*49+t];
    else if (t >= 64 && t < 64+25) wf[49 + (t-64)] = w5[c*25 + (t-64)];
    else if (t >= 96 && t < 96+9)  wf[74 + (t-96)] = w3[c*9 + (t-96)];
    __syncthreads();
    float bias = b7[c] + b5[c] + b3[c];
    for (int p=t; p<NPIX; p+=256) {
        int y = p/HS, x = p%HS;
        float acc = img[p] + bias;
        for (int dy=-3; dy<=3; ++dy){ int yy=y+dy; if (yy<0||yy>=HS) continue;
            for (int dx=-3; dx<=3; ++dx){ int xx=x+dx; if (xx<0||xx>=HS) continue;
                acc += wf[(dy+3)*7+(dx+3)]*img[yy*HS+xx]; } }
        for (int dy=-2; dy<=2; ++dy){ int yy=y+dy; if (yy<0||yy>=HS) continue;
            for (int dx=-2; dx<=2; ++dx){ int xx=x+dx; if (xx<0||xx>=HS) continue;
                acc += wf[49+(dy+2)*5+(dx+2)]*img[yy*HS+xx]; } }
        for (int dy=-1; dy<=1; ++dy){ int yy=y+dy; if (yy<0||yy>=HS) continue;
            for (int dx=-1; dx<=1; ++dx){ int xx=x+dx; if (xx<0||xx>=HS) continue;
                acc += wf[74+(dy+1)*3+(dx+1)]*img[yy*HS+xx]; } }
        im2[((size_t)(b*DIMC)+c)*NPIX + p] = acc;
    }
}

// ---------------- PPEG: LDS-tiled transpose im2[b][c][p] -> h rows ----------------
__global__ void transpose_im2h(const float* __restrict__ im2, float* __restrict__ h)
{
    __shared__ float tile[32][33];
    int p0 = blockIdx.x*32, c0 = blockIdx.y*32, b = blockIdx.z;
    int tx = threadIdx.x & 31, ty = threadIdx.x >> 5; // 32x8
    #pragma unroll
    for (int i=0;i<32;i+=8) {
        int c = c0 + ty + i, p = p0 + tx;
        if (p < NPIX) tile[ty+i][tx] = im2[((size_t)(b*DIMC) + c)*NPIX + p];
    }
    __syncthreads();
    #pragma unroll
    for (int i=0;i<32;i+=8) {
        int p = p0 + ty + i;
        if (p < NPIX) h[((size_t)(b*SEQ) + 1 + p)*DIMC + c0 + tx] = tile[tx][ty+i];
    }
}

// ---------------- final: LN(cls row) @ fc2 + bias -> logits ----------------
__global__ void final_kernel(const float* __restrict__ h, const float* __restrict__ g,
                             const float* __restrict__ bta, const float* __restrict__ fc2w,
                             const float* __restrict__ fc2b, float* __restrict__ out)
{
    int b = blockIdx.x; int t = threadIdx.x; // 512
    __shared__ float red[512];
    const float* x = &h[(size_t)b*SEQ*DIMC];
    float xv = x[t];
    red[t] = xv; __syncthreads();
    for (int s=256;s>0;s>>=1){ if(t<s) red[t]+=red[t+s]; __syncthreads(); }
    float mu = red[0]/512.f; __syncthreads();
    float d = xv - mu;
    red[t] = d*d; __syncthreads();
    for (int s=256;s>0;s>>=1){ if(t<s) red[t]+=red[t+s]; __syncthreads(); }
    float var = red[0]/512.f; __syncthreads();
    float hn = d * (1.f/sqrtf(var+1e-5f)) * g[t] + bta[t];
    for (int c=0;c<2;++c) {
        red[t] = hn * fc2w[t*2+c]; __syncthreads();
        for (int s=256;s>0;s>>=1){ if(t<s) red[t]+=red[t+s]; __syncthreads(); }
        if (t==0) out[b*2+c] = red[0] + fc2b[c];
        __syncthreads();
    }
}

// ================= host =================
extern "C" void kernel_launch(void* const* d_in, const int* in_sizes, int n_in,
                              void* d_out, int out_size, void* d_ws, size_t ws_size,
                              hipStream_t stream)
{
    (void)in_sizes; (void)n_in; (void)out_size; (void)ws_size;
    const float* feats = (const float*)d_in[0];
    const float* fc1_w = (const float*)d_in[1];
    const float* fc1_b = (const float*)d_in[2];
    const float* cls   = (const float*)d_in[3];
    const float* ln_g[2]  = {(const float*)d_in[4],  (const float*)d_in[10]};
    const float* ln_b[2]  = {(const float*)d_in[5],  (const float*)d_in[11]};
    const float* qkv_w[2] = {(const float*)d_in[6],  (const float*)d_in[12]};
    const float* out_w[2] = {(const float*)d_in[7],  (const float*)d_in[13]};
    const float* out_b[2] = {(const float*)d_in[8],  (const float*)d_in[14]};
    const float* res_w[2] = {(const float*)d_in[9],  (const float*)d_in[15]};
    const float* w7 = (const float*)d_in[16]; const float* b7 = (const float*)d_in[17];
    const float* w5 = (const float*)d_in[18]; const float* b5 = (const float*)d_in[19];
    const float* w3 = (const float*)d_in[20]; const float* b3 = (const float*)d_in[21];
    const float* ng = (const float*)d_in[22]; const float* nb = (const float*)d_in[23];
    const float* fc2w = (const float*)d_in[24]; const float* fc2b = (const float*)d_in[25];

    float* ws = (float*)d_ws;
    size_t off = 0;
    float* h    = ws + off; off += (size_t)BATCH*SEQ*DIMC;      // 2,167,808
    float* h0   = ws + off; off += (size_t)BATCH*NSEQ*DIMC;     // 2,097,152
    float* scr  = ws + off; off += (size_t)BATCH*NPAD*1536;     // 6,528,000 scratch (proj/im/im2)
    float* q    = ws + off; off += (size_t)BATCH*NH*NPAD*DHD;
    float* k    = ws + off; off += (size_t)BATCH*NH*NPAD*DHD;
    float* v    = ws + off; off += (size_t)BATCH*NH*NPAD*DHD;
    float* ql   = ws + off; off += (size_t)BATCH*NH*MLM*DHD;
    float* kl   = ws + off; off += (size_t)BATCH*NH*MLM*DHD;
    float* a2   = ws + off; off += (size_t)BATCH*NH*MLM*MLM + 15;
    float* a2i  = ws + off; off += (size_t)BATCH*NH*MLM*MLM + 15;
    float* a3   = ws + off; off += (size_t)BATCH*NH*MLM*NPAD;
    float* left = ws + off; off += (size_t)BATCH*NH*NPAD*MLM;
    float* a3v  = ws + off; off += (size_t)BATCH*NH*MLM*DHD;
    // half-precision hi/lo staging buffers (granule-major). Max A: 4096x1024 halves.
    _Float16* XAh = (_Float16*)(ws + off); off += 2097152;   // 4,194,304 halves
    _Float16* XAl = (_Float16*)(ws + off); off += 2097152;
    _Float16* WBh = (_Float16*)(ws + off); off += 393216;    // 786,432 halves (max 1536x512)
    _Float16* WBl = (_Float16*)(ws + off); off += 393216;
    // scratch aliases
    float* proj = scr;                               // 2,176,000
    float* im   = scr + (size_t)BATCH*NPAD*DIMC;     // 2,166,784
    float* im2  = im  + (size_t)BATCH*DIMC*NPIX;     // 2,166,784 (total 6,509,568 <= 6,528,000)

    float* outp = (float*)d_out;

    // FC1 + relu -> h0  (f16x3 MFMA)
    convA_kernel<<<((size_t)4096*128+255)/256, 256, 0, stream>>>(feats, XAh, XAl, 4096, NIN);
    convB_kernel<<<((size_t)512*128+255)/256, 256, 0, stream>>>(fc1_w, WBh, WBl, DIMC, NIN);
    gemm_mfma<<<dim3(DIMC/128, 4096/128), 256, 0, stream>>>(
        XAh, XAl, WBh, WBl, fc1_b, h0, BATCH*NSEQ, DIMC, NIN, 1, 0, nullptr, nullptr, nullptr);
    // build h
    {
        size_t tot4 = (size_t)BATCH*SEQ*DIMC/4;
        buildh_kernel<<<(tot4+255)/256, 256, 0, stream>>>(h0, cls, h);
    }

    for (int L = 0; L < 2; ++L) {
        float* aw = outp + 4 + (size_t)L*AWSZ;
        // LN -> hi/lo halves (padded rows zeroed), granule-major
        ln_pad_kernel<<<dim3(NPAD, BATCH), 256, 0, stream>>>(h, ln_g[L], ln_b[L], XAh, XAl);
        // qkv GEMM with fused head-split epilogue -> q (scaled), k, v
        convB_kernel<<<((size_t)1536*64+255)/256, 256, 0, stream>>>(qkv_w[L], WBh, WBl, 1536, DIMC);
        gemm_mfma<<<dim3(1536/128, (RA+127)/128), 256, 0, stream>>>(
            XAh, XAl, WBh, WBl, nullptr, nullptr, RA, 1536, DIMC, 0, 1, q, k, v);
        landmark_kernel<<<dim3(MLM, NH, BATCH), 64, 0, stream>>>(q, k, ql, kl);
        a2_kernel<<<dim3(BATCH*NH), 320, 0, stream>>>(ql, kl, a2);
        a3_kernel<<<dim3(MLM, NH, BATCH), 256, 0, stream>>>(ql, k, a3);
        pinv_kernel<<<BATCH*NH, 320, 0, stream>>>(a2, a2i);
        a1_left_kernel<<<dim3(NPAD, NH, BATCH), 64, 0, stream>>>(q, kl, a2i, left);
        a3v_kernel<<<dim3(MLM, NH, BATCH), 64, 0, stream>>>(a3, v, a3v);
        // headout writes hi/lo halves directly (A operand of proj GEMM)
        headout_kernel<<<dim3(NPAD, NH, BATCH), 64, 0, stream>>>(left, a3v, v, res_w[L], XAh, XAl);
        attn_out_kernel<<<dim3((NPAD+511)/512, (NPAD+63)/64, BATCH*NH), 256, 0, stream>>>(left, a3, aw);
        // proj = hout @ out_w + out_b  (f16x3 MFMA)
        convB_kernel<<<((size_t)512*64+255)/256, 256, 0, stream>>>(out_w[L], WBh, WBl, DIMC, DIMC);
        gemm_mfma<<<dim3(DIMC/128, (RA+127)/128), 256, 0, stream>>>(
            XAh, XAl, WBh, WBl, out_b[L], proj, RA, DIMC, DIMC, 0, 0, nullptr, nullptr, nullptr);
        // h += proj[rows 8..]
        {
            size_t tot4 = (size_t)BATCH*SEQ*DIMC/4;
            add_res_kernel<<<(tot4+255)/256, 256, 0, stream>>>(h, proj);
        }
        if (L == 0) {
            // PPEG (all passes coalesced via LDS-tiled transposes)
            transpose_h2im<<<dim3((NPIX+31)/32, DIMC/32, BATCH), 256, 0, stream>>>(h, im);
            ppeg_conv_kernel<<<dim3(DIMC, BATCH), 256, 0, stream>>>(im, w7, b7, w5, b5, w3, b3, im2);
            transpose_im2h<<<dim3((NPIX+31)/32, DIMC/32, BATCH), 256, 0, stream>>>(im2, h);
        }
    }
    final_kernel<<<BATCH, 512, 0, stream>>>(h, ng, nb, fc2w, fc2b, outp);
}